// Round 17
// baseline (531.014 us; speedup 1.0000x reference)
//
#include <hip/hip_runtime.h>
#include <hip/hip_bf16.h>
#include <math.h>

#define B_SZ 16384
#define T_CONV 8
#define HID 256
#define SK 16   // split-K slices for the weight-collapse GEMMs

typedef __bf16 bf16x8 __attribute__((ext_vector_type(8)));
typedef float f32x4 __attribute__((ext_vector_type(4)));

__device__ __forceinline__ float fsigm(float x) { return 1.f / (1.f + __expf(-x)); }
__device__ __forceinline__ float ftanh(float x) {
    float t = __expf(-2.f * fabsf(x));
    float r = (1.f - t) / (1.f + t);
    return x >= 0.f ? r : -r;
}

// ---------------------------------------------------------------------------
// collapse_conv: fold nv->conv into small per-dt matrices (linearity).
// ---------------------------------------------------------------------------
__global__ void collapse_conv(const float* __restrict__ W_rp, const float* __restrict__ b_rp,
                              const float* __restrict__ W_co, const float* __restrict__ b_co,
                              const float* __restrict__ conv_w, const float* __restrict__ conv_b,
                              float* __restrict__ Crp, float* __restrict__ Cco,
                              float* __restrict__ cb2)
{
    int idx = blockIdx.x * 256 + threadIdx.x;
    if (idx < 1152) {
        int o = idx & 31, k = (idx >> 5) % 12, dt = idx / 384;
        float a = 0.f;
        for (int c = 0; c < 32; c++) a += W_rp[k * 32 + c] * conv_w[(dt * 40 + c) * 32 + o];
        Crp[idx] = a;
    } else if (idx < 1344) {
        int j = idx - 1152;
        int o = j & 31, k = (j >> 5) & 1, dt = j / 64;
        float a = 0.f;
        for (int c = 0; c < 8; c++) a += W_co[k * 8 + c] * conv_w[(dt * 40 + 32 + c) * 32 + o];
        Cco[j] = a;
    } else if (idx < 1376) {
        int o = idx - 1344;
        float a = conv_b[o];
        for (int dt = 0; dt < 3; dt++) {
            for (int c = 0; c < 32; c++) a += b_rp[c] * conv_w[(dt * 40 + c) * 32 + o];
            for (int c = 0; c < 8; c++)  a += b_co[c] * conv_w[(dt * 40 + 32 + c) * 32 + o];
        }
        cb2[o] = a;
    }
}

// ---------------------------------------------------------------------------
// Feature kernel v3: gathers + collapsed conv (42 MAC/output) -> Xp bf16
// ---------------------------------------------------------------------------
#define FB_SAMPLES 4
__global__ __launch_bounds__(256) void feature_kernel(
    const int* __restrict__ region_idx, const int* __restrict__ poi_idx,
    const int* __restrict__ car_idx, const int* __restrict__ week_idx,
    const int* __restrict__ time_idx, const float* __restrict__ coords,
    const float* __restrict__ region_tbl, const float* __restrict__ poi_tbl,
    const float* __restrict__ car_tbl, const float* __restrict__ week_tbl,
    const float* __restrict__ time_tbl,
    const float* __restrict__ Crp, const float* __restrict__ Cco,
    const float* __restrict__ cb2, __bf16* __restrict__ Xp)
{
    __shared__ float s_crp[1152];
    __shared__ float s_cco[192];
    __shared__ float s_cb2[32];
    __shared__ float s_rp[FB_SAMPLES][10][12];
    __shared__ float s_co[FB_SAMPLES][10][2];
    __shared__ float s_emb[FB_SAMPLES][27];

    int tid = threadIdx.x;
    for (int i = tid; i < 1152; i += 256) s_crp[i] = Crp[i];
    if (tid < 192) s_cco[tid] = Cco[tid];
    else if (tid < 224) s_cb2[tid - 192] = cb2[tid - 192];

    int s  = tid >> 6;
    int lt = tid & 63;
    int b  = blockIdx.x * FB_SAMPLES + s;

    if (lt < 27) {
        float v;
        if (lt < 16)      v = car_tbl[(size_t)car_idx[b] * 16 + lt];
        else if (lt < 19) v = week_tbl[week_idx[b] * 3 + (lt - 16)];
        else              v = time_tbl[time_idx[b] * 8 + (lt - 19)];
        s_emb[s][lt] = tanhf(v);
    }
    for (int i = lt; i < 120; i += 64) {
        int t = i / 12, k = i % 12;
        float v;
        if (k < 8) v = region_tbl[(size_t)region_idx[b * 10 + t] * 8 + k];
        else       v = poi_tbl[poi_idx[b * 10 + t] * 4 + (k - 8)];
        s_rp[s][t][k] = v;
    }
    for (int i = lt; i < 20; i += 64) {
        int t = i >> 1, k = i & 1;
        s_co[s][t][k] = coords[(size_t)(b * 10 + t) * 2 + k];
    }
    __syncthreads();

    for (int i = lt; i < 256; i += 64) {
        int t = i >> 5, o = i & 31;
        float acc = s_cb2[o];
        #pragma unroll
        for (int dt = 0; dt < 3; dt++) {
            #pragma unroll
            for (int k = 0; k < 12; k++)
                acc += s_rp[s][t + dt][k] * s_crp[(dt * 12 + k) * 32 + o];
            acc += s_co[s][t + dt][0] * s_cco[(dt * 2 + 0) * 32 + o]
                 + s_co[s][t + dt][1] * s_cco[(dt * 2 + 1) * 32 + o];
        }
        acc = acc > 0.f ? acc : expm1f(acc);
        Xp[(size_t)(b * 8 + t) * 64 + o] = (__bf16)acc;
    }
    for (int i = lt; i < 216; i += 64) {
        int t = i / 27, j = i % 27;
        Xp[(size_t)(b * 8 + t) * 64 + 32 + j] = (__bf16)s_emb[s][j];
    }
    for (int i = lt; i < 40; i += 64) {
        int t = i / 5, j = i % 5;
        Xp[(size_t)(b * 8 + t) * 64 + 59 + j] = (__bf16)0.f;
    }
}

// ---------------------------------------------------------------------------
// LSTM step body (wave-per-gate + LDS exchange; epilogue reads re-mapped to
// one-column-per-lane scalars: GL read bank = (row*4 + col) mod 32 -> 2-way).
// ---------------------------------------------------------------------------
#define AST 40   // LDS A-row stride in bf16 (80B -> 2-way banks, free)
__device__ __forceinline__ void lstm_body(
    unsigned char* smem,
    const __bf16* __restrict__ A1, int lda1, int K1,
    const __bf16* __restrict__ A2, int lda2,
    const __bf16* __restrict__ WS,
    const float* __restrict__ bias, float* __restrict__ cst,
    __bf16* __restrict__ hb,
    int KT, int is_t0)
{
    __bf16* As = (__bf16*)smem;                 // [2][64*AST] = 10.2 KB
    float*  GL = (float*)smem;                  // [4][16][68]

    int tid = threadIdx.x;
    int bm  = blockIdx.y * 64;
    int bnf = blockIdx.x * 4;
    int bn  = blockIdx.x * 64;
    int l   = tid & 63;
    int g   = tid >> 6;                         // wave == gate
    int fr  = l & 15;
    int fo  = (l >> 4) * 8;

    f32x4 acc[4][4] = {};

    int s_row = tid >> 2;                       // 64 rows, 4 thr/row
    int s_q   = tid & 3;                        // 8-elem (16B) quarter

    auto asrc = [&](int kt) -> const __bf16* {
        int k0 = kt * 32;
        if (k0 < K1) return A1 + (size_t)(bm + s_row) * lda1 + k0 + s_q * 8;
        return A2 + (size_t)(bm + s_row) * lda2 + (k0 - K1) + s_q * 8;
    };
    const __bf16* wbase = WS + ((size_t)g * 16 + bnf) * 512 + (size_t)l * 8;

    { *(bf16x8*)&As[s_row * AST + s_q * 8] = *(const bf16x8*)asrc(0); }
    bf16x8 bcur[4];
    #pragma unroll
    for (int j = 0; j < 4; j++) bcur[j] = *(const bf16x8*)(wbase + j * 512);

    for (int kt = 0; kt < KT; kt++) {
        int cb = kt & 1;
        bf16x8 bnxt[4], an0;
        if (kt + 1 < KT) {
            an0 = *(const bf16x8*)asrc(kt + 1);
            const __bf16* wb = wbase + (size_t)(kt + 1) * 32768;
            #pragma unroll
            for (int j = 0; j < 4; j++) bnxt[j] = *(const bf16x8*)(wb + j * 512);
        }
        __syncthreads();
        bf16x8 af[4];
        #pragma unroll
        for (int mf = 0; mf < 4; mf++)
            af[mf] = *(bf16x8*)&As[cb * 64 * AST + (mf * 16 + fr) * AST + fo];
        #pragma unroll
        for (int mf = 0; mf < 4; mf++)
            #pragma unroll
            for (int j = 0; j < 4; j++)
                acc[mf][j] = __builtin_amdgcn_mfma_f32_16x16x32_bf16(
                    af[mf], bcur[j], acc[mf][j], 0, 0, 0);
        if (kt + 1 < KT) {
            *(bf16x8*)&As[(cb ^ 1) * 64 * AST + s_row * AST + s_q * 8] = an0;
            #pragma unroll
            for (int j = 0; j < 4; j++) bcur[j] = bnxt[j];
        }
    }

    // ---- epilogue (fully unrolled; reads = 1 col/lane -> 2-way banks)
    int rbase = (l >> 4) * 4;
    int col   = tid & 63;          // read/pointwise column
    int rq    = tid >> 6;          // row-quad (0..3): rows rq*4..rq*4+3
    float bi  = bias[bn + col];
    float bf_ = bias[256 + bn + col];
    float bg  = bias[512 + bn + col];
    float bo  = bias[768 + bn + col];

    #pragma unroll
    for (int mf = 0; mf < 4; mf++) {
        __syncthreads();
        #pragma unroll
        for (int j = 0; j < 4; j++)
            #pragma unroll
            for (int e = 0; e < 4; e++)
                GL[(g * 16 + rbase + e) * 68 + j * 16 + fr] = acc[mf][j][e];
        __syncthreads();

        #pragma unroll
        for (int r = 0; r < 4; r++) {
            int row = rq * 4 + r;
            size_t moff = ((size_t)bm + mf * 16 + row) * 256 + bn + col;
            float gi = GL[(0 * 16 + row) * 68 + col];
            float gf = GL[(1 * 16 + row) * 68 + col];
            float gg = GL[(2 * 16 + row) * 68 + col];
            float go = GL[(3 * 16 + row) * 68 + col];
            float cd = is_t0 ? 0.f : cst[moff];
            float i_ = fsigm(gi + bi);
            float f_ = fsigm(gf + bf_);
            float g_ = ftanh(gg + bg);
            float o_ = fsigm(go + bo);
            float c_ = f_ * cd + i_ * g_;
            cst[moff] = c_;
            hb[moff] = (__bf16)(o_ * ftanh(c_));
        }
    }
}

__global__ __launch_bounds__(256, 2) void lstm_fused(
    const __bf16* __restrict__ A1, int lda1, int K1,
    const __bf16* __restrict__ A2, int lda2,
    const __bf16* __restrict__ WS,
    const float* __restrict__ bias, float* __restrict__ cst,
    __bf16* __restrict__ hb, int KT, int is_t0)
{
    __shared__ __align__(16) unsigned char smem[4 * 16 * 68 * 4];  // 17.4 KB
    lstm_body(smem, A1, lda1, K1, A2, lda2, WS, bias, cst, hb, KT, is_t0);
}

// Combined launch: z=0 -> L1(t), z=1 -> L0(t+1). Independent sub-problems;
// double-buffered h0/h1 make this race-free regardless of block scheduling.
__global__ __launch_bounds__(256, 2) void lstm_dual(
    const __bf16* A1a, int lda1a, int K1a, const __bf16* A2a, int lda2a,
    const __bf16* WSa, const float* biasa, float* csta, __bf16* hba, int KTa, int t0a,
    const __bf16* A1b, int lda1b, int K1b, const __bf16* A2b, int lda2b,
    const __bf16* WSb, const float* biasb, float* cstb, __bf16* hbb, int KTb, int t0b)
{
    __shared__ __align__(16) unsigned char smem[4 * 16 * 68 * 4];  // 17.4 KB
    if (blockIdx.z == 0)
        lstm_body(smem, A1a, lda1a, K1a, A2a, lda2a, WSa, biasa, csta, hba, KTa, t0a);
    else
        lstm_body(smem, A1b, lda1b, K1b, A2b, lda2b, WSb, biasb, cstb, hbb, KTb, t0b);
}

// ---------------------------------------------------------------------------
// Head GEMM via MFMA
// ---------------------------------------------------------------------------
#define HAST 40
__global__ __launch_bounds__(256, 2) void head_mfma(
    const __bf16* __restrict__ A,
    const __bf16* __restrict__ WS,
    const float* __restrict__ bias, float* __restrict__ out)
{
    __shared__ __align__(16) __bf16 As[2][128 * HAST];

    int tid = threadIdx.x;
    int bm  = blockIdx.y * 128;
    int l   = tid & 63;
    int wv  = tid >> 6;
    int fr  = l & 15;
    int fo  = (l >> 4) * 8;
    int nfb = blockIdx.x * 16 + wv * 4;

    f32x4 acc[8][4] = {};

    int s_row  = tid >> 1;
    int s_half = tid & 1;
    const __bf16* abase = A + (size_t)(bm + s_row) * 256 + s_half * 16;
    const __bf16* wbase = WS + (size_t)nfb * 512 + (size_t)l * 8;

    {
        bf16x8 v0 = *(const bf16x8*)abase;
        bf16x8 v1 = *(const bf16x8*)(abase + 8);
        *(bf16x8*)&As[0][s_row * HAST + s_half * 16]     = v0;
        *(bf16x8*)&As[0][s_row * HAST + s_half * 16 + 8] = v1;
    }
    bf16x8 bcur[4];
    #pragma unroll
    for (int j = 0; j < 4; j++) bcur[j] = *(const bf16x8*)(wbase + j * 512);

    #pragma unroll
    for (int kt = 0; kt < 8; kt++) {
        int cb = kt & 1;
        bf16x8 bnxt[4], an0, an1;
        if (kt + 1 < 8) {
            const __bf16* s = abase + (kt + 1) * 32;
            an0 = *(const bf16x8*)s;
            an1 = *(const bf16x8*)(s + 8);
            const __bf16* wb = wbase + (size_t)(kt + 1) * 16384;
            #pragma unroll
            for (int j = 0; j < 4; j++) bnxt[j] = *(const bf16x8*)(wb + j * 512);
        }
        __syncthreads();
        bf16x8 af[8];
        #pragma unroll
        for (int mf = 0; mf < 8; mf++)
            af[mf] = *(bf16x8*)&As[cb][(mf * 16 + fr) * HAST + fo];
        #pragma unroll
        for (int mf = 0; mf < 8; mf++)
            #pragma unroll
            for (int j = 0; j < 4; j++)
                acc[mf][j] = __builtin_amdgcn_mfma_f32_16x16x32_bf16(
                    af[mf], bcur[j], acc[mf][j], 0, 0, 0);
        if (kt + 1 < 8) {
            *(bf16x8*)&As[cb ^ 1][s_row * HAST + s_half * 16]     = an0;
            *(bf16x8*)&As[cb ^ 1][s_row * HAST + s_half * 16 + 8] = an1;
            #pragma unroll
            for (int j = 0; j < 4; j++) bcur[j] = bnxt[j];
        }
    }

    int rbase = (l >> 4) * 4;
    #pragma unroll
    for (int mf = 0; mf < 8; mf++) {
        #pragma unroll
        for (int j = 0; j < 4; j++) {
            int n = (nfb + j) * 16 + fr;
            float bv = bias[n];
            #pragma unroll
            for (int e = 0; e < 4; e++) {
                size_t m = (size_t)bm + mf * 16 + rbase + e;
                out[m * 512 + n] = acc[mf][j][e] + bv;
            }
        }
    }
}

// ---------------------------------------------------------------------------
// Split-K fp32 GEMM (weight collapse) + reduce
// ---------------------------------------------------------------------------
__global__ __launch_bounds__(256) void gemm_nn_sk(
    const float* __restrict__ A, int lda, const float* __restrict__ Bm, int ldb,
    float* __restrict__ P, int M, int N, int K)
{
    __shared__ float As[16][68];
    __shared__ float Bs[16][68];
    int tid = threadIdx.x;
    int tx = tid & 15, ty = tid >> 4;
    int bm = blockIdx.y * 64, bn = blockIdx.x * 64;
    int klen = K / SK;
    int kbeg = blockIdx.z * klen;

    float acc[4][4] = {};

    for (int k0 = kbeg; k0 < kbeg + klen; k0 += 16) {
        for (int i = tid; i < 1024; i += 256) {
            int k = i & 15, m = i >> 4;
            As[k][m] = A[(size_t)(bm + m) * lda + k0 + k];
        }
        for (int i = tid; i < 1024; i += 256) {
            int n = i & 63, k = i >> 6;
            Bs[k][n] = Bm[(size_t)(k0 + k) * ldb + bn + n];
        }
        __syncthreads();
        #pragma unroll
        for (int kk = 0; kk < 16; kk++) {
            float4 a = *(const float4*)&As[kk][ty * 4];
            float4 b = *(const float4*)&Bs[kk][tx * 4];
            float av[4] = {a.x, a.y, a.z, a.w};
            float bv[4] = {b.x, b.y, b.z, b.w};
            #pragma unroll
            for (int i = 0; i < 4; i++)
                #pragma unroll
                for (int j = 0; j < 4; j++)
                    acc[i][j] += av[i] * bv[j];
        }
        __syncthreads();
    }

    float* Pd = P + (size_t)blockIdx.z * M * N;
    #pragma unroll
    for (int i = 0; i < 4; i++) {
        int m = bm + ty * 4 + i;
        #pragma unroll
        for (int j = 0; j < 4; j++) {
            int n = bn + tx * 4 + j;
            Pd[(size_t)m * N + n] = acc[i][j];
        }
    }
}

__global__ __launch_bounds__(256) void reduce_sk(
    const float* __restrict__ P, int MN, float* __restrict__ C)
{
    int i = blockIdx.x * 256 + threadIdx.x;
    if (i >= MN) return;
    float a = 0.f;
    #pragma unroll
    for (int s = 0; s < SK; s++) a += P[(size_t)s * MN + i];
    C[i] = a;
}

// ---------------------------------------------------------------------------
__global__ __launch_bounds__(256) void vecmat(
    const float* __restrict__ v, const float* __restrict__ M, int ldb, int K,
    const float* __restrict__ bias, float* __restrict__ outv)
{
    __shared__ float red[4][64];
    int l = threadIdx.x & 63;
    int w = threadIdx.x >> 6;
    int n = blockIdx.x * 64 + l;
    int kpw = K >> 2;
    int k0 = w * kpw;

    float p[8] = {};
    for (int k = k0; k < k0 + kpw; k += 8) {
        #pragma unroll
        for (int u = 0; u < 8; u++)
            p[u] += v[k + u] * M[(size_t)(k + u) * ldb + n];
    }
    red[w][l] = ((p[0] + p[1]) + (p[2] + p[3])) + ((p[4] + p[5]) + (p[6] + p[7]));
    __syncthreads();
    if (w == 0)
        outv[n] = red[0][l] + red[1][l] + red[2][l] + red[3][l]
                + (bias ? bias[n] : 0.f);
}

// ---------------------------------------------------------------------------
// Helpers / packers
// ---------------------------------------------------------------------------
__global__ void add_biases(const float* __restrict__ bih0, const float* __restrict__ bhh0,
                           const float* __restrict__ bih1, const float* __restrict__ bhh1,
                           float* __restrict__ b01)
{
    int i = blockIdx.x * 256 + threadIdx.x;
    if (i < 1024)       b01[i] = bih0[i] + bhh0[i];
    else if (i < 2048)  b01[i] = bih1[i - 1024] + bhh1[i - 1024];
}

__global__ void pack_w01_swz(const float* __restrict__ Wih0, const float* __restrict__ Whh0,
                             const float* __restrict__ Wih1, const float* __restrict__ Whh1,
                             __bf16* __restrict__ WS0, __bf16* __restrict__ WS1)
{
    const int N0 = 10 * 4 * 16 * 64 * 8;
    const int N1 = 16 * 4 * 16 * 64 * 8;
    int idx = blockIdx.x * 256 + threadIdx.x;
    if (idx < N0) {
        int e  = idx & 7;
        int l  = (idx >> 3) & 63;
        int nf = (idx >> 9) & 15;
        int g  = (idx >> 13) & 3;
        int kt = idx >> 15;
        int n_row = g * 256 + nf * 16 + (l & 15);
        int k = kt * 32 + ((l >> 4) * 8) + e;
        float v = (k < 59) ? Wih0[(size_t)n_row * 59 + k]
                : (k < 64) ? 0.f
                           : Whh0[(size_t)n_row * 256 + (k - 64)];
        WS0[idx] = (__bf16)v;
    } else if (idx < N0 + N1) {
        int j = idx - N0;
        int e  = j & 7;
        int l  = (j >> 3) & 63;
        int nf = (j >> 9) & 15;
        int g  = (j >> 13) & 3;
        int kt = j >> 15;
        int n_row = g * 256 + nf * 16 + (l & 15);
        int k = kt * 32 + ((l >> 4) * 8) + e;
        float v = (k < 256) ? Wih1[(size_t)n_row * 256 + k]
                            : Whh1[(size_t)n_row * 256 + (k - 256)];
        WS1[j] = (__bf16)v;
    }
}

__global__ void pack_head_swz(const float* __restrict__ Wc, __bf16* __restrict__ WS)
{
    int idx = blockIdx.x * 256 + threadIdx.x;
    if (idx >= 8 * 32 * 64 * 8) return;
    int e  = idx & 7;
    int l  = (idx >> 3) & 63;
    int nf = (idx >> 9) & 31;
    int kt = idx >> 14;
    int n = nf * 16 + (l & 15);
    int k = kt * 32 + ((l >> 4) * 8) + e;
    WS[idx] = (__bf16)Wc[(size_t)k * 512 + n];
}

// ---------------------------------------------------------------------------
extern "C" void kernel_launch(void* const* d_in, const int* in_sizes, int n_in,
                              void* d_out, int out_size, void* d_ws, size_t ws_size,
                              hipStream_t stream)
{
    const int*   region_idx = (const int*)d_in[0];
    const int*   poi_idx    = (const int*)d_in[1];
    const int*   car_idx    = (const int*)d_in[2];
    const int*   week_idx   = (const int*)d_in[3];
    const int*   time_idx   = (const int*)d_in[4];
    const float* coords     = (const float*)d_in[5];
    const float* region_tbl = (const float*)d_in[6];
    const float* poi_tbl    = (const float*)d_in[7];
    const float* car_tbl    = (const float*)d_in[8];
    const float* week_tbl   = (const float*)d_in[9];
    const float* time_tbl   = (const float*)d_in[10];
    const float* W_rp   = (const float*)d_in[11];
    const float* b_rp   = (const float*)d_in[12];
    const float* W_co   = (const float*)d_in[13];
    const float* b_co   = (const float*)d_in[14];
    const float* conv_w = (const float*)d_in[15];
    const float* conv_b = (const float*)d_in[16];
    const float* Wih0 = (const float*)d_in[17];
    const float* Whh0 = (const float*)d_in[18];
    const float* bih0 = (const float*)d_in[19];
    const float* bhh0 = (const float*)d_in[20];
    const float* Wih1 = (const float*)d_in[21];
    const float* Whh1 = (const float*)d_in[22];
    const float* bih1 = (const float*)d_in[23];
    const float* bhh1 = (const float*)d_in[24];
    const float* W1 = (const float*)d_in[25];
    const float* b1 = (const float*)d_in[26];
    const float* W2 = (const float*)d_in[27];
    const float* b2 = (const float*)d_in[28];
    const float* W3 = (const float*)d_in[29];
    const float* b3 = (const float*)d_in[30];
    float* out = (float*)d_out;

    // ---- workspace layout ----
    char* ws = (char*)d_ws;
    size_t off = 0;
    auto alloc = [&](size_t bytes) -> char* {
        char* p = ws + off;
        off = (off + bytes + 255) & ~(size_t)255;
        return p;
    };
    __bf16* Xp   = (__bf16*)alloc((size_t)B_SZ * 8 * 64 * 2);
    __bf16* H0a  = (__bf16*)alloc((size_t)B_SZ * HID * 2);
    __bf16* H0b  = (__bf16*)alloc((size_t)B_SZ * HID * 2);
    __bf16* H1a  = (__bf16*)alloc((size_t)B_SZ * HID * 2);
    __bf16* H1b  = (__bf16*)alloc((size_t)B_SZ * HID * 2);
    float*  c0   = (float*)alloc((size_t)B_SZ * HID * 4);
    float*  c1   = (float*)alloc((size_t)B_SZ * HID * 4);
    __bf16* WS0  = (__bf16*)alloc((size_t)10 * 4 * 16 * 64 * 8 * 2);
    __bf16* WS1  = (__bf16*)alloc((size_t)16 * 4 * 16 * 64 * 8 * 2);
    __bf16* WSH  = (__bf16*)alloc((size_t)8 * 32 * 64 * 8 * 2);
    float*  T1    = (float*)alloc(256 * 1024 * 4);
    float*  tb1   = (float*)alloc(1024 * 4);
    float*  Wcomb = (float*)alloc(256 * 512 * 4);
    float*  bcomb = (float*)alloc(512 * 4);
    float*  b01   = (float*)alloc(2048 * 4);
    float*  Crp   = (float*)alloc(1152 * 4);
    float*  Cco   = (float*)alloc(192 * 4);
    float*  cb2   = (float*)alloc(32 * 4);
    float*  Psk   = (float*)alloc((size_t)SK * 256 * 1024 * 4);
    (void)ws_size;
    float* bias0 = b01;
    float* bias1 = b01 + 1024;
    __bf16* H0[2] = {H0a, H0b};
    __bf16* H1[2] = {H1a, H1b};

    // ---- weight prep ----
    pack_w01_swz<<<3328, 256, 0, stream>>>(Wih0, Whh0, Wih1, Whh1, WS0, WS1);
    add_biases<<<8, 256, 0, stream>>>(bih0, bhh0, bih1, bhh1, b01);
    collapse_conv<<<6, 256, 0, stream>>>(W_rp, b_rp, W_co, b_co, conv_w, conv_b,
                                         Crp, Cco, cb2);

    // ---- collapse head: Wcomb = W1@W2@W3, bcomb = (b1@W2+b2)@W3+b3 ----
    gemm_nn_sk<<<dim3(16, 4, SK), 256, 0, stream>>>(W1, 512, W2, 1024, Psk, 256, 1024, 512);
    reduce_sk<<<(256 * 1024 + 255) / 256, 256, 0, stream>>>(Psk, 256 * 1024, T1);
    vecmat<<<16, 256, 0, stream>>>(b1, W2, 1024, 512, b2, tb1);
    gemm_nn_sk<<<dim3(8, 4, SK), 256, 0, stream>>>(T1, 1024, W3, 512, Psk, 256, 512, 1024);
    reduce_sk<<<(256 * 512 + 255) / 256, 256, 0, stream>>>(Psk, 256 * 512, Wcomb);
    vecmat<<<8, 256, 0, stream>>>(tb1, W3, 512, 1024, b3, bcomb);
    pack_head_swz<<<512, 256, 0, stream>>>(Wcomb, WSH);

    // ---- features -> Xp bf16 ----
    feature_kernel<<<B_SZ / FB_SAMPLES, 256, 0, stream>>>(
        region_idx, poi_idx, car_idx, week_idx, time_idx, coords,
        region_tbl, poi_tbl, car_tbl, week_tbl, time_tbl,
        Crp, Cco, cb2, Xp);

    // ---- LSTM: ping-pong h buffers; combined {L1(t), L0(t+1)} launches ----
    dim3 lstm_grid(4, B_SZ / 64);
    dim3 dual_grid(4, B_SZ / 64, 2);

    // L0(0)
    lstm_fused<<<lstm_grid, 256, 0, stream>>>(
        Xp, 512, 64, H0[1], HID, WS0, bias0, c0, H0[0], 2, 1);

    for (int t = 0; t < T_CONV - 1; t++) {
        int pc = t & 1, pn = (t + 1) & 1;
        lstm_dual<<<dual_grid, 256, 0, stream>>>(
            // z=0: L1(t): A=[H0[t] | H1[t-1]] -> H1[t]
            H0[pc], HID, 256, H1[pn], HID, WS1, bias1, c1, H1[pc],
            (t == 0) ? 8 : 16, t == 0,
            // z=1: L0(t+1): A=[Xp_{t+1} | H0[t]] -> H0[t+1]
            Xp + (size_t)(t + 1) * 64, 512, 64, H0[pc], HID, WS0, bias0, c0, H0[pn],
            10, 0);
    }

    // L1(7): reads H0[1], H1[0] -> writes H1[1]
    lstm_fused<<<lstm_grid, 256, 0, stream>>>(
        H0[1], HID, 256, H1[0], HID, WS1, bias1, c1, H1[1], 16, 0);

    // ---- head: out = H1[1] @ Wcomb + bcomb ----
    head_mfma<<<dim3(2, 128), 256, 0, stream>>>(H1[1], WSH, bcomb, out);
}

// Round 18
// 502.011 us; speedup vs baseline: 1.0578x; 1.0578x over previous
//
#include <hip/hip_runtime.h>
#include <hip/hip_bf16.h>
#include <math.h>

#define B_SZ 16384
#define T_CONV 8
#define HID 256
#define SK 16   // split-K slices for the weight-collapse GEMMs

typedef __bf16 bf16x8 __attribute__((ext_vector_type(8)));
typedef float f32x4 __attribute__((ext_vector_type(4)));

__device__ __forceinline__ float fsigm(float x) { return 1.f / (1.f + __expf(-x)); }
__device__ __forceinline__ float ftanh(float x) {
    float t = __expf(-2.f * fabsf(x));
    float r = (1.f - t) / (1.f + t);
    return x >= 0.f ? r : -r;
}

// ---------------------------------------------------------------------------
// collapse_conv: fold nv->conv into small per-dt matrices (linearity).
// ---------------------------------------------------------------------------
__global__ void collapse_conv(const float* __restrict__ W_rp, const float* __restrict__ b_rp,
                              const float* __restrict__ W_co, const float* __restrict__ b_co,
                              const float* __restrict__ conv_w, const float* __restrict__ conv_b,
                              float* __restrict__ Crp, float* __restrict__ Cco,
                              float* __restrict__ cb2)
{
    int idx = blockIdx.x * 256 + threadIdx.x;
    if (idx < 1152) {
        int o = idx & 31, k = (idx >> 5) % 12, dt = idx / 384;
        float a = 0.f;
        for (int c = 0; c < 32; c++) a += W_rp[k * 32 + c] * conv_w[(dt * 40 + c) * 32 + o];
        Crp[idx] = a;
    } else if (idx < 1344) {
        int j = idx - 1152;
        int o = j & 31, k = (j >> 5) & 1, dt = j / 64;
        float a = 0.f;
        for (int c = 0; c < 8; c++) a += W_co[k * 8 + c] * conv_w[(dt * 40 + 32 + c) * 32 + o];
        Cco[j] = a;
    } else if (idx < 1376) {
        int o = idx - 1344;
        float a = conv_b[o];
        for (int dt = 0; dt < 3; dt++) {
            for (int c = 0; c < 32; c++) a += b_rp[c] * conv_w[(dt * 40 + c) * 32 + o];
            for (int c = 0; c < 8; c++)  a += b_co[c] * conv_w[(dt * 40 + 32 + c) * 32 + o];
        }
        cb2[o] = a;
    }
}

// ---------------------------------------------------------------------------
// Feature kernel v3: gathers + collapsed conv (42 MAC/output) -> Xp bf16
// ---------------------------------------------------------------------------
#define FB_SAMPLES 4
__global__ __launch_bounds__(256) void feature_kernel(
    const int* __restrict__ region_idx, const int* __restrict__ poi_idx,
    const int* __restrict__ car_idx, const int* __restrict__ week_idx,
    const int* __restrict__ time_idx, const float* __restrict__ coords,
    const float* __restrict__ region_tbl, const float* __restrict__ poi_tbl,
    const float* __restrict__ car_tbl, const float* __restrict__ week_tbl,
    const float* __restrict__ time_tbl,
    const float* __restrict__ Crp, const float* __restrict__ Cco,
    const float* __restrict__ cb2, __bf16* __restrict__ Xp)
{
    __shared__ float s_crp[1152];
    __shared__ float s_cco[192];
    __shared__ float s_cb2[32];
    __shared__ float s_rp[FB_SAMPLES][10][12];
    __shared__ float s_co[FB_SAMPLES][10][2];
    __shared__ float s_emb[FB_SAMPLES][27];

    int tid = threadIdx.x;
    for (int i = tid; i < 1152; i += 256) s_crp[i] = Crp[i];
    if (tid < 192) s_cco[tid] = Cco[tid];
    else if (tid < 224) s_cb2[tid - 192] = cb2[tid - 192];

    int s  = tid >> 6;
    int lt = tid & 63;
    int b  = blockIdx.x * FB_SAMPLES + s;

    if (lt < 27) {
        float v;
        if (lt < 16)      v = car_tbl[(size_t)car_idx[b] * 16 + lt];
        else if (lt < 19) v = week_tbl[week_idx[b] * 3 + (lt - 16)];
        else              v = time_tbl[time_idx[b] * 8 + (lt - 19)];
        s_emb[s][lt] = tanhf(v);
    }
    for (int i = lt; i < 120; i += 64) {
        int t = i / 12, k = i % 12;
        float v;
        if (k < 8) v = region_tbl[(size_t)region_idx[b * 10 + t] * 8 + k];
        else       v = poi_tbl[poi_idx[b * 10 + t] * 4 + (k - 8)];
        s_rp[s][t][k] = v;
    }
    for (int i = lt; i < 20; i += 64) {
        int t = i >> 1, k = i & 1;
        s_co[s][t][k] = coords[(size_t)(b * 10 + t) * 2 + k];
    }
    __syncthreads();

    for (int i = lt; i < 256; i += 64) {
        int t = i >> 5, o = i & 31;
        float acc = s_cb2[o];
        #pragma unroll
        for (int dt = 0; dt < 3; dt++) {
            #pragma unroll
            for (int k = 0; k < 12; k++)
                acc += s_rp[s][t + dt][k] * s_crp[(dt * 12 + k) * 32 + o];
            acc += s_co[s][t + dt][0] * s_cco[(dt * 2 + 0) * 32 + o]
                 + s_co[s][t + dt][1] * s_cco[(dt * 2 + 1) * 32 + o];
        }
        acc = acc > 0.f ? acc : expm1f(acc);
        Xp[(size_t)(b * 8 + t) * 64 + o] = (__bf16)acc;
    }
    for (int i = lt; i < 216; i += 64) {
        int t = i / 27, j = i % 27;
        Xp[(size_t)(b * 8 + t) * 64 + 32 + j] = (__bf16)s_emb[s][j];
    }
    for (int i = lt; i < 40; i += 64) {
        int t = i / 5, j = i % 5;
        Xp[(size_t)(b * 8 + t) * 64 + 59 + j] = (__bf16)0.f;
    }
}

// ---------------------------------------------------------------------------
// LSTM step body (R14 best: wave-per-gate, LDS exchange, f32x4 epilogue).
// ---------------------------------------------------------------------------
#define AST 40   // LDS A-row stride in bf16 (80B -> 2-way banks, free)
__device__ __forceinline__ void lstm_body(
    unsigned char* smem,
    const __bf16* __restrict__ A1, int lda1, int K1,
    const __bf16* __restrict__ A2, int lda2,
    const __bf16* __restrict__ WS,
    const float* __restrict__ bias, float* __restrict__ cst,
    __bf16* __restrict__ hb,
    int KT, int is_t0)
{
    __bf16* As = (__bf16*)smem;                 // [2][64*AST] = 10.2 KB
    float*  GL = (float*)smem;                  // [4][16][68]

    int tid = threadIdx.x;
    int bm  = blockIdx.y * 64;
    int bnf = blockIdx.x * 4;
    int bn  = blockIdx.x * 64;
    int l   = tid & 63;
    int g   = tid >> 6;                         // wave == gate
    int fr  = l & 15;
    int fo  = (l >> 4) * 8;

    f32x4 acc[4][4] = {};

    int s_row = tid >> 2;                       // 64 rows, 4 thr/row
    int s_q   = tid & 3;                        // 8-elem (16B) quarter

    auto asrc = [&](int kt) -> const __bf16* {
        int k0 = kt * 32;
        if (k0 < K1) return A1 + (size_t)(bm + s_row) * lda1 + k0 + s_q * 8;
        return A2 + (size_t)(bm + s_row) * lda2 + (k0 - K1) + s_q * 8;
    };
    const __bf16* wbase = WS + ((size_t)g * 16 + bnf) * 512 + (size_t)l * 8;

    { *(bf16x8*)&As[s_row * AST + s_q * 8] = *(const bf16x8*)asrc(0); }
    bf16x8 bcur[4];
    #pragma unroll
    for (int j = 0; j < 4; j++) bcur[j] = *(const bf16x8*)(wbase + j * 512);

    for (int kt = 0; kt < KT; kt++) {
        int cb = kt & 1;
        bf16x8 bnxt[4], an0;
        if (kt + 1 < KT) {
            an0 = *(const bf16x8*)asrc(kt + 1);
            const __bf16* wb = wbase + (size_t)(kt + 1) * 32768;
            #pragma unroll
            for (int j = 0; j < 4; j++) bnxt[j] = *(const bf16x8*)(wb + j * 512);
        }
        __syncthreads();
        bf16x8 af[4];
        #pragma unroll
        for (int mf = 0; mf < 4; mf++)
            af[mf] = *(bf16x8*)&As[cb * 64 * AST + (mf * 16 + fr) * AST + fo];
        #pragma unroll
        for (int mf = 0; mf < 4; mf++)
            #pragma unroll
            for (int j = 0; j < 4; j++)
                acc[mf][j] = __builtin_amdgcn_mfma_f32_16x16x32_bf16(
                    af[mf], bcur[j], acc[mf][j], 0, 0, 0);
        if (kt + 1 < KT) {
            *(bf16x8*)&As[(cb ^ 1) * 64 * AST + s_row * AST + s_q * 8] = an0;
            #pragma unroll
            for (int j = 0; j < 4; j++) bcur[j] = bnxt[j];
        }
    }

    // ---- epilogue (fully unrolled: static acc indexing, rule #20)
    int rbase = (l >> 4) * 4;
    int prow  = tid >> 4;
    int pcol  = (tid & 15) * 4;
    f32x4 bs[4];
    #pragma unroll
    for (int gg = 0; gg < 4; gg++)
        bs[gg] = *(const f32x4*)&bias[gg * 256 + bn + pcol];

    #pragma unroll
    for (int mf = 0; mf < 4; mf++) {
        __syncthreads();
        #pragma unroll
        for (int j = 0; j < 4; j++)
            #pragma unroll
            for (int e = 0; e < 4; e++)
                GL[(g * 16 + rbase + e) * 68 + j * 16 + fr] = acc[mf][j][e];
        __syncthreads();

        size_t moff = ((size_t)bm + mf * 16 + prow) * 256 + bn + pcol;
        f32x4 gi = *(f32x4*)&GL[(0 * 16 + prow) * 68 + pcol];
        f32x4 gf = *(f32x4*)&GL[(1 * 16 + prow) * 68 + pcol];
        f32x4 gg = *(f32x4*)&GL[(2 * 16 + prow) * 68 + pcol];
        f32x4 go = *(f32x4*)&GL[(3 * 16 + prow) * 68 + pcol];
        f32x4 cold = {0.f, 0.f, 0.f, 0.f};
        if (!is_t0) cold = *(f32x4*)&cst[moff];
        f32x4 cn;
        union { unsigned short u[4]; unsigned long long v; } hx;
        #pragma unroll
        for (int q = 0; q < 4; q++) {
            float i_ = fsigm(gi[q] + bs[0][q]);
            float f_ = fsigm(gf[q] + bs[1][q]);
            float g_ = ftanh(gg[q] + bs[2][q]);
            float o_ = fsigm(go[q] + bs[3][q]);
            float c_ = f_ * cold[q] + i_ * g_;
            cn[q] = c_;
            float h_ = o_ * ftanh(c_);
            __bf16 hv = (__bf16)h_;
            hx.u[q] = *(unsigned short*)&hv;
        }
        *(f32x4*)&cst[moff] = cn;
        *(unsigned long long*)&hb[moff] = hx.v;
    }
}

__global__ __launch_bounds__(256, 2) void lstm_fused(
    const __bf16* __restrict__ A1, int lda1, int K1,
    const __bf16* __restrict__ A2, int lda2,
    const __bf16* __restrict__ WS,
    const float* __restrict__ bias, float* __restrict__ cst,
    __bf16* __restrict__ hb, int KT, int is_t0)
{
    __shared__ __align__(16) unsigned char smem[4 * 16 * 68 * 4];  // 17.4 KB
    lstm_body(smem, A1, lda1, K1, A2, lda2, WS, bias, cst, hb, KT, is_t0);
}

// Combined launch: z=0 -> L1(t), z=1 -> L0(t+1). Independent sub-problems;
// double-buffered h0/h1 make this race-free regardless of block scheduling.
__global__ __launch_bounds__(256, 2) void lstm_dual(
    const __bf16* A1a, int lda1a, int K1a, const __bf16* A2a, int lda2a,
    const __bf16* WSa, const float* biasa, float* csta, __bf16* hba, int KTa, int t0a,
    const __bf16* A1b, int lda1b, int K1b, const __bf16* A2b, int lda2b,
    const __bf16* WSb, const float* biasb, float* cstb, __bf16* hbb, int KTb, int t0b)
{
    __shared__ __align__(16) unsigned char smem[4 * 16 * 68 * 4];  // 17.4 KB
    if (blockIdx.z == 0)
        lstm_body(smem, A1a, lda1a, K1a, A2a, lda2a, WSa, biasa, csta, hba, KTa, t0a);
    else
        lstm_body(smem, A1b, lda1b, K1b, A2b, lda2b, WSb, biasb, cstb, hbb, KTb, t0b);
}

// ---------------------------------------------------------------------------
// Head GEMM via MFMA
// ---------------------------------------------------------------------------
#define HAST 40
__global__ __launch_bounds__(256, 2) void head_mfma(
    const __bf16* __restrict__ A,
    const __bf16* __restrict__ WS,
    const float* __restrict__ bias, float* __restrict__ out)
{
    __shared__ __align__(16) __bf16 As[2][128 * HAST];

    int tid = threadIdx.x;
    int bm  = blockIdx.y * 128;
    int l   = tid & 63;
    int wv  = tid >> 6;
    int fr  = l & 15;
    int fo  = (l >> 4) * 8;
    int nfb = blockIdx.x * 16 + wv * 4;

    f32x4 acc[8][4] = {};

    int s_row  = tid >> 1;
    int s_half = tid & 1;
    const __bf16* abase = A + (size_t)(bm + s_row) * 256 + s_half * 16;
    const __bf16* wbase = WS + (size_t)nfb * 512 + (size_t)l * 8;

    {
        bf16x8 v0 = *(const bf16x8*)abase;
        bf16x8 v1 = *(const bf16x8*)(abase + 8);
        *(bf16x8*)&As[0][s_row * HAST + s_half * 16]     = v0;
        *(bf16x8*)&As[0][s_row * HAST + s_half * 16 + 8] = v1;
    }
    bf16x8 bcur[4];
    #pragma unroll
    for (int j = 0; j < 4; j++) bcur[j] = *(const bf16x8*)(wbase + j * 512);

    #pragma unroll
    for (int kt = 0; kt < 8; kt++) {
        int cb = kt & 1;
        bf16x8 bnxt[4], an0, an1;
        if (kt + 1 < 8) {
            const __bf16* s = abase + (kt + 1) * 32;
            an0 = *(const bf16x8*)s;
            an1 = *(const bf16x8*)(s + 8);
            const __bf16* wb = wbase + (size_t)(kt + 1) * 16384;
            #pragma unroll
            for (int j = 0; j < 4; j++) bnxt[j] = *(const bf16x8*)(wb + j * 512);
        }
        __syncthreads();
        bf16x8 af[8];
        #pragma unroll
        for (int mf = 0; mf < 8; mf++)
            af[mf] = *(bf16x8*)&As[cb][(mf * 16 + fr) * HAST + fo];
        #pragma unroll
        for (int mf = 0; mf < 8; mf++)
            #pragma unroll
            for (int j = 0; j < 4; j++)
                acc[mf][j] = __builtin_amdgcn_mfma_f32_16x16x32_bf16(
                    af[mf], bcur[j], acc[mf][j], 0, 0, 0);
        if (kt + 1 < 8) {
            *(bf16x8*)&As[cb ^ 1][s_row * HAST + s_half * 16]     = an0;
            *(bf16x8*)&As[cb ^ 1][s_row * HAST + s_half * 16 + 8] = an1;
            #pragma unroll
            for (int j = 0; j < 4; j++) bcur[j] = bnxt[j];
        }
    }

    int rbase = (l >> 4) * 4;
    #pragma unroll
    for (int mf = 0; mf < 8; mf++) {
        #pragma unroll
        for (int j = 0; j < 4; j++) {
            int n = (nfb + j) * 16 + fr;
            float bv = bias[n];
            #pragma unroll
            for (int e = 0; e < 4; e++) {
                size_t m = (size_t)bm + mf * 16 + rbase + e;
                out[m * 512 + n] = acc[mf][j][e] + bv;
            }
        }
    }
}

// ---------------------------------------------------------------------------
// Split-K fp32 GEMM (weight collapse) + reduce
// ---------------------------------------------------------------------------
__global__ __launch_bounds__(256) void gemm_nn_sk(
    const float* __restrict__ A, int lda, const float* __restrict__ Bm, int ldb,
    float* __restrict__ P, int M, int N, int K)
{
    __shared__ float As[16][68];
    __shared__ float Bs[16][68];
    int tid = threadIdx.x;
    int tx = tid & 15, ty = tid >> 4;
    int bm = blockIdx.y * 64, bn = blockIdx.x * 64;
    int klen = K / SK;
    int kbeg = blockIdx.z * klen;

    float acc[4][4] = {};

    for (int k0 = kbeg; k0 < kbeg + klen; k0 += 16) {
        for (int i = tid; i < 1024; i += 256) {
            int k = i & 15, m = i >> 4;
            As[k][m] = A[(size_t)(bm + m) * lda + k0 + k];
        }
        for (int i = tid; i < 1024; i += 256) {
            int n = i & 63, k = i >> 6;
            Bs[k][n] = Bm[(size_t)(k0 + k) * ldb + bn + n];
        }
        __syncthreads();
        #pragma unroll
        for (int kk = 0; kk < 16; kk++) {
            float4 a = *(const float4*)&As[kk][ty * 4];
            float4 b = *(const float4*)&Bs[kk][tx * 4];
            float av[4] = {a.x, a.y, a.z, a.w};
            float bv[4] = {b.x, b.y, b.z, b.w};
            #pragma unroll
            for (int i = 0; i < 4; i++)
                #pragma unroll
                for (int j = 0; j < 4; j++)
                    acc[i][j] += av[i] * bv[j];
        }
        __syncthreads();
    }

    float* Pd = P + (size_t)blockIdx.z * M * N;
    #pragma unroll
    for (int i = 0; i < 4; i++) {
        int m = bm + ty * 4 + i;
        #pragma unroll
        for (int j = 0; j < 4; j++) {
            int n = bn + tx * 4 + j;
            Pd[(size_t)m * N + n] = acc[i][j];
        }
    }
}

__global__ __launch_bounds__(256) void reduce_sk(
    const float* __restrict__ P, int MN, float* __restrict__ C)
{
    int i = blockIdx.x * 256 + threadIdx.x;
    if (i >= MN) return;
    float a = 0.f;
    #pragma unroll
    for (int s = 0; s < SK; s++) a += P[(size_t)s * MN + i];
    C[i] = a;
}

// ---------------------------------------------------------------------------
__global__ __launch_bounds__(256) void vecmat(
    const float* __restrict__ v, const float* __restrict__ M, int ldb, int K,
    const float* __restrict__ bias, float* __restrict__ outv)
{
    __shared__ float red[4][64];
    int l = threadIdx.x & 63;
    int w = threadIdx.x >> 6;
    int n = blockIdx.x * 64 + l;
    int kpw = K >> 2;
    int k0 = w * kpw;

    float p[8] = {};
    for (int k = k0; k < k0 + kpw; k += 8) {
        #pragma unroll
        for (int u = 0; u < 8; u++)
            p[u] += v[k + u] * M[(size_t)(k + u) * ldb + n];
    }
    red[w][l] = ((p[0] + p[1]) + (p[2] + p[3])) + ((p[4] + p[5]) + (p[6] + p[7]));
    __syncthreads();
    if (w == 0)
        outv[n] = red[0][l] + red[1][l] + red[2][l] + red[3][l]
                + (bias ? bias[n] : 0.f);
}

// ---------------------------------------------------------------------------
// Helpers / packers
// ---------------------------------------------------------------------------
__global__ void add_biases(const float* __restrict__ bih0, const float* __restrict__ bhh0,
                           const float* __restrict__ bih1, const float* __restrict__ bhh1,
                           float* __restrict__ b01)
{
    int i = blockIdx.x * 256 + threadIdx.x;
    if (i < 1024)       b01[i] = bih0[i] + bhh0[i];
    else if (i < 2048)  b01[i] = bih1[i - 1024] + bhh1[i - 1024];
}

__global__ void pack_w01_swz(const float* __restrict__ Wih0, const float* __restrict__ Whh0,
                             const float* __restrict__ Wih1, const float* __restrict__ Whh1,
                             __bf16* __restrict__ WS0, __bf16* __restrict__ WS1)
{
    const int N0 = 10 * 4 * 16 * 64 * 8;
    const int N1 = 16 * 4 * 16 * 64 * 8;
    int idx = blockIdx.x * 256 + threadIdx.x;
    if (idx < N0) {
        int e  = idx & 7;
        int l  = (idx >> 3) & 63;
        int nf = (idx >> 9) & 15;
        int g  = (idx >> 13) & 3;
        int kt = idx >> 15;
        int n_row = g * 256 + nf * 16 + (l & 15);
        int k = kt * 32 + ((l >> 4) * 8) + e;
        float v = (k < 59) ? Wih0[(size_t)n_row * 59 + k]
                : (k < 64) ? 0.f
                           : Whh0[(size_t)n_row * 256 + (k - 64)];
        WS0[idx] = (__bf16)v;
    } else if (idx < N0 + N1) {
        int j = idx - N0;
        int e  = j & 7;
        int l  = (j >> 3) & 63;
        int nf = (j >> 9) & 15;
        int g  = (j >> 13) & 3;
        int kt = j >> 15;
        int n_row = g * 256 + nf * 16 + (l & 15);
        int k = kt * 32 + ((l >> 4) * 8) + e;
        float v = (k < 256) ? Wih1[(size_t)n_row * 256 + k]
                            : Whh1[(size_t)n_row * 256 + (k - 256)];
        WS1[j] = (__bf16)v;
    }
}

__global__ void pack_head_swz(const float* __restrict__ Wc, __bf16* __restrict__ WS)
{
    int idx = blockIdx.x * 256 + threadIdx.x;
    if (idx >= 8 * 32 * 64 * 8) return;
    int e  = idx & 7;
    int l  = (idx >> 3) & 63;
    int nf = (idx >> 9) & 31;
    int kt = idx >> 14;
    int n = nf * 16 + (l & 15);
    int k = kt * 32 + ((l >> 4) * 8) + e;
    WS[idx] = (__bf16)Wc[(size_t)k * 512 + n];
}

// ---------------------------------------------------------------------------
extern "C" void kernel_launch(void* const* d_in, const int* in_sizes, int n_in,
                              void* d_out, int out_size, void* d_ws, size_t ws_size,
                              hipStream_t stream)
{
    const int*   region_idx = (const int*)d_in[0];
    const int*   poi_idx    = (const int*)d_in[1];
    const int*   car_idx    = (const int*)d_in[2];
    const int*   week_idx   = (const int*)d_in[3];
    const int*   time_idx   = (const int*)d_in[4];
    const float* coords     = (const float*)d_in[5];
    const float* region_tbl = (const float*)d_in[6];
    const float* poi_tbl    = (const float*)d_in[7];
    const float* car_tbl    = (const float*)d_in[8];
    const float* week_tbl   = (const float*)d_in[9];
    const float* time_tbl   = (const float*)d_in[10];
    const float* W_rp   = (const float*)d_in[11];
    const float* b_rp   = (const float*)d_in[12];
    const float* W_co   = (const float*)d_in[13];
    const float* b_co   = (const float*)d_in[14];
    const float* conv_w = (const float*)d_in[15];
    const float* conv_b = (const float*)d_in[16];
    const float* Wih0 = (const float*)d_in[17];
    const float* Whh0 = (const float*)d_in[18];
    const float* bih0 = (const float*)d_in[19];
    const float* bhh0 = (const float*)d_in[20];
    const float* Wih1 = (const float*)d_in[21];
    const float* Whh1 = (const float*)d_in[22];
    const float* bih1 = (const float*)d_in[23];
    const float* bhh1 = (const float*)d_in[24];
    const float* W1 = (const float*)d_in[25];
    const float* b1 = (const float*)d_in[26];
    const float* W2 = (const float*)d_in[27];
    const float* b2 = (const float*)d_in[28];
    const float* W3 = (const float*)d_in[29];
    const float* b3 = (const float*)d_in[30];
    float* out = (float*)d_out;

    // ---- workspace layout ----
    char* ws = (char*)d_ws;
    size_t off = 0;
    auto alloc = [&](size_t bytes) -> char* {
        char* p = ws + off;
        off = (off + bytes + 255) & ~(size_t)255;
        return p;
    };
    __bf16* Xp   = (__bf16*)alloc((size_t)B_SZ * 8 * 64 * 2);
    __bf16* H0a  = (__bf16*)alloc((size_t)B_SZ * HID * 2);
    __bf16* H0b  = (__bf16*)alloc((size_t)B_SZ * HID * 2);
    __bf16* H1a  = (__bf16*)alloc((size_t)B_SZ * HID * 2);
    __bf16* H1b  = (__bf16*)alloc((size_t)B_SZ * HID * 2);
    float*  c0   = (float*)alloc((size_t)B_SZ * HID * 4);
    float*  c1   = (float*)alloc((size_t)B_SZ * HID * 4);
    __bf16* WS0  = (__bf16*)alloc((size_t)10 * 4 * 16 * 64 * 8 * 2);
    __bf16* WS1  = (__bf16*)alloc((size_t)16 * 4 * 16 * 64 * 8 * 2);
    __bf16* WSH  = (__bf16*)alloc((size_t)8 * 32 * 64 * 8 * 2);
    float*  T1    = (float*)alloc(256 * 1024 * 4);
    float*  tb1   = (float*)alloc(1024 * 4);
    float*  Wcomb = (float*)alloc(256 * 512 * 4);
    float*  bcomb = (float*)alloc(512 * 4);
    float*  b01   = (float*)alloc(2048 * 4);
    float*  Crp   = (float*)alloc(1152 * 4);
    float*  Cco   = (float*)alloc(192 * 4);
    float*  cb2   = (float*)alloc(32 * 4);
    float*  Psk   = (float*)alloc((size_t)SK * 256 * 1024 * 4);
    (void)ws_size;
    float* bias0 = b01;
    float* bias1 = b01 + 1024;
    __bf16* H0[2] = {H0a, H0b};
    __bf16* H1[2] = {H1a, H1b};

    // ---- weight prep ----
    pack_w01_swz<<<3328, 256, 0, stream>>>(Wih0, Whh0, Wih1, Whh1, WS0, WS1);
    add_biases<<<8, 256, 0, stream>>>(bih0, bhh0, bih1, bhh1, b01);
    collapse_conv<<<6, 256, 0, stream>>>(W_rp, b_rp, W_co, b_co, conv_w, conv_b,
                                         Crp, Cco, cb2);

    // ---- collapse head: Wcomb = W1@W2@W3, bcomb = (b1@W2+b2)@W3+b3 ----
    gemm_nn_sk<<<dim3(16, 4, SK), 256, 0, stream>>>(W1, 512, W2, 1024, Psk, 256, 1024, 512);
    reduce_sk<<<(256 * 1024 + 255) / 256, 256, 0, stream>>>(Psk, 256 * 1024, T1);
    vecmat<<<16, 256, 0, stream>>>(b1, W2, 1024, 512, b2, tb1);
    gemm_nn_sk<<<dim3(8, 4, SK), 256, 0, stream>>>(T1, 1024, W3, 512, Psk, 256, 512, 1024);
    reduce_sk<<<(256 * 512 + 255) / 256, 256, 0, stream>>>(Psk, 256 * 512, Wcomb);
    vecmat<<<8, 256, 0, stream>>>(tb1, W3, 512, 1024, b3, bcomb);
    pack_head_swz<<<512, 256, 0, stream>>>(Wcomb, WSH);

    // ---- features -> Xp bf16 ----
    feature_kernel<<<B_SZ / FB_SAMPLES, 256, 0, stream>>>(
        region_idx, poi_idx, car_idx, week_idx, time_idx, coords,
        region_tbl, poi_tbl, car_tbl, week_tbl, time_tbl,
        Crp, Cco, cb2, Xp);

    // ---- LSTM: ping-pong h buffers; combined {L1(t), L0(t+1)} launches ----
    dim3 lstm_grid(4, B_SZ / 64);
    dim3 dual_grid(4, B_SZ / 64, 2);

    // L0(0)
    lstm_fused<<<lstm_grid, 256, 0, stream>>>(
        Xp, 512, 64, H0[1], HID, WS0, bias0, c0, H0[0], 2, 1);

    for (int t = 0; t < T_CONV - 1; t++) {
        int pc = t & 1, pn = (t + 1) & 1;
        lstm_dual<<<dual_grid, 256, 0, stream>>>(
            // z=0: L1(t): A=[H0[t] | H1[t-1]] -> H1[t]
            H0[pc], HID, 256, H1[pn], HID, WS1, bias1, c1, H1[pc],
            (t == 0) ? 8 : 16, t == 0,
            // z=1: L0(t+1): A=[Xp_{t+1} | H0[t]] -> H0[t+1]
            Xp + (size_t)(t + 1) * 64, 512, 64, H0[pc], HID, WS0, bias0, c0, H0[pn],
            10, 0);
    }

    // L1(7): reads H0[1], H1[0] -> writes H1[1]
    lstm_fused<<<lstm_grid, 256, 0, stream>>>(
        H0[1], HID, 256, H1[0], HID, WS1, bias1, c1, H1[1], 16, 0);

    // ---- head: out = H1[1] @ Wcomb + bcomb ----
    head_mfma<<<dim3(2, 128), 256, 0, stream>>>(H1[1], WSH, bcomb, out);
}